// Round 9
// baseline (126.867 us; speedup 1.0000x reference)
//
#include <hip/hip_runtime.h>
#include <stdint.h>

#define K_DIM 1024
#define N_DIM 1024
#define BM 256
#define BN 256
#define BK4 32
#define NT (K_DIM / BK4)           // 32 K-tiles
#define UNIT4_U32 ((BM + BN) * 16) // 32 KB per ring unit (A 16KB + B 16KB)

#define AS1 __attribute__((address_space(1)))
#define AS3 __attribute__((address_space(3)))

typedef __attribute__((ext_vector_type(4))) float f32x4;
typedef __attribute__((ext_vector_type(8))) short bf16x8;
typedef __attribute__((ext_vector_type(4))) uint32_t u32x4;

// round-half-up to bf16, pack two: low 16 = a, high 16 = b
__device__ __forceinline__ uint32_t pack_bf16(float a, float b) {
  uint32_t ua = __builtin_bit_cast(uint32_t, a) + 0x8000u;
  uint32_t ub = __builtin_bit_cast(uint32_t, b) + 0x8000u;
  return __builtin_amdgcn_perm(ub, ua, 0x07060302u);
}

__device__ __forceinline__ float wbin1(float v, float kkv, float aav) {
  float t = v * kkv;
  t = fminf(fmaxf(t, -1.0f), 1.0f);
  return t * aav;
}

// ---------------- kernel 1: w_bin = bf16(aa*clamp(kk*w,-1,1)) into ws ------
__global__ __launch_bounds__(256) void wconv(const float* __restrict__ w,
                                             const float* __restrict__ kkp,
                                             const float* __restrict__ aap,
                                             uint32_t* __restrict__ wb) {
  const float kkv = kkp[0];
  const float aav = aap[0];
  const int g = blockIdx.x * 256 + threadIdx.x;  // 16 floats per thread
  const f32x4* src = (const f32x4*)(w + (size_t)g * 16);
  f32x4 v0 = src[0], v1 = src[1], v2 = src[2], v3 = src[3];
  uint32_t p[8];
#pragma unroll
  for (int i = 0; i < 4; ++i) {
    f32x4 v = i == 0 ? v0 : (i == 1 ? v1 : (i == 2 ? v2 : v3));
    p[2 * i] = pack_bf16(wbin1(v[0], kkv, aav), wbin1(v[1], kkv, aav));
    p[2 * i + 1] = pack_bf16(wbin1(v[2], kkv, aav), wbin1(v[3], kkv, aav));
  }
  u32x4* dst = (u32x4*)(wb + (size_t)g * 8);
  dst[0] = u32x4{p[0], p[1], p[2], p[3]};
  dst[1] = u32x4{p[4], p[5], p[6], p[7]};
}

// ---------------- kernel 2: x fp32 -> bf16 (packed) into ws ----------------
__global__ __launch_bounds__(256) void xconv(const float* __restrict__ x,
                                             uint32_t* __restrict__ xb) {
  const size_t g = (size_t)blockIdx.x * 256 + threadIdx.x;  // 16 floats
  const f32x4* src = (const f32x4*)(x + g * 16);
  f32x4 v0 = src[0], v1 = src[1], v2 = src[2], v3 = src[3];
  uint32_t p[8];
  p[0] = pack_bf16(v0[0], v0[1]); p[1] = pack_bf16(v0[2], v0[3]);
  p[2] = pack_bf16(v1[0], v1[1]); p[3] = pack_bf16(v1[2], v1[3]);
  p[4] = pack_bf16(v2[0], v2[1]); p[5] = pack_bf16(v2[2], v2[3]);
  p[6] = pack_bf16(v3[0], v3[1]); p[7] = pack_bf16(v3[2], v3[3]);
  u32x4* dst = (u32x4*)(xb + g * 8);
  dst[0] = u32x4{p[0], p[1], p[2], p[3]};
  dst[1] = u32x4{p[4], p[5], p[6], p[7]};
}

// ---------------- kernel 3 (fast): 4-ring counted-vmcnt GEMM ---------------
// 256x256 tile, 512 thr = 8 waves (2 wave-rows x 4 wave-cols), wave 128x64
// out = 8x4 frags, BK=32, 32 K-tiles. LDS ring of 4 units (A[256][32] +
// B[256][32] bf16 = 32 KB each, 128 KB total). Stage unit t+3 during tile t
// (4 gload_lds/wave: 2 A at ph0, 2 B at ph1); boundary vmcnt(8) retires t+1
// only — vmcnt never 0 until the tail, ~3 tiles (~6 phases) of cover/unit.
// 2 phases/tile x 16 MFMA.
// LDS layout: row = 4 slots x 16B; phys_slot = kg ^ ((row>>1)&3) -> every
// 16-lane ds_read group hits each bank-quad exactly 2x (free, m136). DMA
// source pre-applies the same involution; dest stays linear (rule #21).
__global__ __launch_bounds__(512, 2) void binlin_gemm4r(
    const uint32_t* __restrict__ xb, const uint32_t* __restrict__ wb,
    const float* __restrict__ bias, float* __restrict__ out) {
  __shared__ uint32_t lds[4 * UNIT4_U32];  // 128 KB

  const int tid = threadIdx.x;

  // bijective XCD swizzle (grid=512): 4 n-blocks of an m-panel -> same L2
  const int per = gridDim.x >> 3;
  const int logical = (blockIdx.x & 7) * per + (blockIdx.x >> 3);
  const int mIdx = logical >> 2;  // N_DIM/BN = 4
  const int nIdx = logical & 3;
  const int row0 = mIdx * BM;
  const int col0 = nIdx * BN;

  const int w8 = tid >> 6;
  const int lane = tid & 63;
  // staging source mapping (16 rows / op): lane -> row lane>>2, logical
  // slot s = (lane&3) ^ ((lane>>3)&3)  [inverse of phys = kg ^ ((row>>1)&3)]
  const int rl = lane >> 2;
  const int sl = (lane & 3) ^ ((lane >> 3) & 3);
  const uint32_t* ga_base =
      xb + (size_t)(row0 + w8 * 32 + rl) * (K_DIM / 2) + sl * 4;
  const uint32_t* gb_base =
      wb + (size_t)(col0 + w8 * 32 + rl) * (K_DIM / 2) + sl * 4;

  const int wr = w8 >> 2;  // 0..1 (m half)
  const int wc = w8 & 3;   // 0..3 (n quarter)
  const int cl = lane & 15;
  const int kg = lane >> 4;  // 16B k-slot (0..3)

  f32x4 acc[8][4] = {};
  bf16x8 af[8], bfr[2];

  // stage 16 A-rows (op c in 0..1) of K-tile kt into unit SD
#define STAGE_A1(kt, SD, c)                                               \
  __builtin_amdgcn_global_load_lds(                                       \
      (const AS1 uint32_t*)(ga_base + (size_t)((c)*16) * (K_DIM / 2) +    \
                            (kt)*16),                                     \
      (AS3 uint32_t*)((SD) + (w8 * 32 + (c)*16) * 16), 16, 0, 0)

#define STAGE_B1(kt, SD, c)                                               \
  __builtin_amdgcn_global_load_lds(                                       \
      (const AS1 uint32_t*)(gb_base + (size_t)((c)*16) * (K_DIM / 2) +    \
                            (kt)*16),                                     \
      (AS3 uint32_t*)((SD) + BM * 16 + (w8 * 32 + (c)*16) * 16), 16, 0, 0)

#define READ_AF(AB)                                                            \
  _Pragma("unroll") for (int m = 0; m < 8; ++m) {                              \
    int rr = wr * 128 + m * 16 + cl;                                           \
    af[m] =                                                                    \
        *(const bf16x8*)((AB) + rr * 16 + ((kg ^ ((rr >> 1) & 3)) * 4));       \
  }

#define READ_BF(BB, NH)                                                        \
  _Pragma("unroll") for (int n = 0; n < 2; ++n) {                              \
    int rr = wc * 64 + ((NH)*2 + n) * 16 + cl;                                 \
    bfr[n] =                                                                   \
        *(const bf16x8*)((BB) + rr * 16 + ((kg ^ ((rr >> 1) & 3)) * 4));       \
  }

#define PHTAIL(NH)                                                             \
  __builtin_amdgcn_s_barrier();                                                \
  asm volatile("s_waitcnt lgkmcnt(0)" ::: "memory");                           \
  __builtin_amdgcn_sched_barrier(0);                                           \
  __builtin_amdgcn_s_setprio(1);                                               \
  _Pragma("unroll") for (int m = 0; m < 8; ++m)                                \
  _Pragma("unroll") for (int n = 0; n < 2; ++n)                                \
  acc[m][(NH)*2 + n] = __builtin_amdgcn_mfma_f32_16x16x32_bf16(                \
      af[m], bfr[n], acc[m][(NH)*2 + n], 0, 0, 0);                             \
  __builtin_amdgcn_s_setprio(0);

  // prologue: stage units 0,1,2 (12 ops, issue order = unit order), retire
  // unit 0 only (vmcnt(8) keeps units 1,2 in flight)
#pragma unroll
  for (int u = 0; u < 3; ++u) {
    uint32_t* SD = &lds[u * UNIT4_U32];
    STAGE_A1(u, SD, 0);
    STAGE_A1(u, SD, 1);
    STAGE_B1(u, SD, 0);
    STAGE_B1(u, SD, 1);
  }
  asm volatile("s_waitcnt vmcnt(8)" ::: "memory");
  __builtin_amdgcn_s_barrier();

  for (int t = 0; t < NT; ++t) {
    const uint32_t* AB = &lds[(t & 3) * UNIT4_U32];
    const uint32_t* BB = AB + BM * 16;
    uint32_t* SD = &lds[((t + 3) & 3) * UNIT4_U32];
    const bool more = (t + 3) < NT;
    // ph0: n-cols 0-1 — stage A half of unit t+3
    READ_AF(AB);
    READ_BF(BB, 0);
    if (more) {
      STAGE_A1(t + 3, SD, 0);
      STAGE_A1(t + 3, SD, 1);
    }
    PHTAIL(0);
    __builtin_amdgcn_s_barrier();
    // ph1: n-cols 2-3 — stage B half of unit t+3
    READ_BF(BB, 1);
    if (more) {
      STAGE_B1(t + 3, SD, 0);
      STAGE_B1(t + 3, SD, 1);
    }
    PHTAIL(1);
    // boundary: retire unit t+1 only; deeper units stay in flight
    if (t < NT - 3) {
      asm volatile("s_waitcnt vmcnt(8)" ::: "memory");
    } else if (t == NT - 3) {
      asm volatile("s_waitcnt vmcnt(4)" ::: "memory");
    } else if (t == NT - 2) {
      asm volatile("s_waitcnt vmcnt(0)" ::: "memory");
    }
    __builtin_amdgcn_s_barrier();
  }

  // epilogue: bias + fp32 store
#pragma unroll
  for (int n = 0; n < 4; ++n) {
    int col = col0 + wc * 64 + n * 16 + cl;
    float bv = bias[col];
#pragma unroll
    for (int m = 0; m < 8; ++m) {
      int rowb = row0 + wr * 128 + m * 16 + kg * 4;
#pragma unroll
      for (int i = 0; i < 4; ++i) {
        out[(size_t)(rowb + i) * N_DIM + col] = acc[m][n][i] + bv;
      }
    }
  }
#undef STAGE_A1
#undef STAGE_B1
#undef READ_AF
#undef READ_BF
#undef PHTAIL
}

// ---------------- fallback GEMM (fused conversion, used when ws small) -----
#define BK 64
#define NK (K_DIM / BK)
__global__ __launch_bounds__(512, 2) void binlin_gemm_fb(
    const float* __restrict__ x, const uint32_t* __restrict__ wb,
    const float* __restrict__ bias, float* __restrict__ out) {
  __shared__ uint32_t lds[2][(BM + BN) * 32];

  const int tid = threadIdx.x;
  const int per = gridDim.x >> 3;
  const int logical = (blockIdx.x & 7) * per + (blockIdx.x >> 3);
  const int mIdx = logical >> 2;
  const int nIdx = logical & 3;
  const int row0 = mIdx * BM;
  const int col0 = nIdx * BN;

  const int r = tid >> 1;
  const int h = tid & 1;
  const int sw = r & 7;
  const float* ga = x + (size_t)(row0 + r) * K_DIM + h * 32;
  const int aoff = r * 32;

  const int w8 = tid >> 6;
  const int lane = tid & 63;
  const int brow = lane >> 3;
  const int bslot = (lane & 7) ^ brow;
  const uint32_t* gb_base =
      wb + (size_t)(col0 + w8 * 32 + brow) * (K_DIM / 2) + bslot * 4;
  const int boff = (w8 * 32) * 32;

  const int wr = w8 >> 2;
  const int wc = w8 & 3;
  const int cl = lane & 15;
  const int kg = lane >> 4;

  f32x4 acc[8][4] = {};
  f32x4 ra[8];

#define LOADA(kt)                                                \
  {                                                              \
    const f32x4* pa = (const f32x4*)(ga + (kt)*BK);              \
    _Pragma("unroll") for (int i = 0; i < 8; ++i) ra[i] = pa[i]; \
  }
#define WRITEA(buf)                                                       \
  {                                                                       \
    uint32_t* lap = &lds[buf][0] + aoff;                                  \
    _Pragma("unroll") for (int j = 0; j < 4; ++j) {                       \
      u32x4 pk = {pack_bf16(ra[2 * j][0], ra[2 * j][1]),                  \
                  pack_bf16(ra[2 * j][2], ra[2 * j][3]),                  \
                  pack_bf16(ra[2 * j + 1][0], ra[2 * j + 1][1]),          \
                  pack_bf16(ra[2 * j + 1][2], ra[2 * j + 1][3])};         \
      *(u32x4*)(lap + (((h * 4 + j) ^ sw) * 4)) = pk;                     \
    }                                                                     \
  }
#define STAGEB(kt, buf)                                                    \
  {                                                                        \
    uint32_t* lbp = &lds[buf][BM * 32] + boff;                             \
    _Pragma("unroll") for (int c = 0; c < 4; ++c) {                        \
      __builtin_amdgcn_global_load_lds(                                    \
          (const AS1 uint32_t*)(gb_base + (size_t)(c * 8) * (K_DIM / 2) +  \
                                (kt)*32),                                  \
          (AS3 uint32_t*)(lbp + c * 8 * 32), 16, 0, 0);                    \
    }                                                                      \
  }
#define COMPUTE(buf)                                                           \
  {                                                                            \
    const uint32_t* A = &lds[buf][0];                                          \
    const uint32_t* B = &lds[buf][BM * 32];                                    \
    _Pragma("unroll") for (int ks = 0; ks < 2; ++ks) {                         \
      bf16x8 bfr[4];                                                           \
      _Pragma("unroll") for (int n = 0; n < 4; ++n) {                          \
        int rr = wc * 64 + n * 16 + cl;                                        \
        bfr[n] =                                                               \
            *(const bf16x8*)(B + rr * 32 + (((ks * 4 + kg) ^ (rr & 7)) * 4));  \
      }                                                                        \
      _Pragma("unroll") for (int mh = 0; mh < 2; ++mh) {                       \
        bf16x8 af[4];                                                          \
        _Pragma("unroll") for (int m = 0; m < 4; ++m) {                        \
          int rr = wr * 128 + (mh * 4 + m) * 16 + cl;                          \
          af[m] =                                                              \
              *(const bf16x8*)(A + rr * 32 + (((ks * 4 + kg) ^ (rr & 7)) * 4));\
        }                                                                      \
        __builtin_amdgcn_s_setprio(1);                                         \
        _Pragma("unroll") for (int m = 0; m < 4; ++m)                          \
            _Pragma("unroll") for (int n = 0; n < 4; ++n)                      \
                acc[mh * 4 + m][n] = __builtin_amdgcn_mfma_f32_16x16x32_bf16(  \
                    af[m], bfr[n], acc[mh * 4 + m][n], 0, 0, 0);               \
        __builtin_amdgcn_s_setprio(0);                                         \
      }                                                                        \
    }                                                                          \
  }

  LOADA(0);
  STAGEB(0, 0);
  WRITEA(0);
  asm volatile("s_waitcnt vmcnt(0) lgkmcnt(0)" ::: "memory");
  __builtin_amdgcn_s_barrier();

  for (int kt2 = 0; kt2 < NK; kt2 += 2) {
    LOADA(kt2 + 1);
    STAGEB(kt2 + 1, 1);
    asm volatile("s_waitcnt vmcnt(12)" ::: "memory");
    __builtin_amdgcn_s_barrier();
    __builtin_amdgcn_sched_barrier(0);
    COMPUTE(0);
    WRITEA(1);
    asm volatile("s_waitcnt lgkmcnt(0)" ::: "memory");
    if (kt2 + 2 < NK) {
      LOADA(kt2 + 2);
      STAGEB(kt2 + 2, 0);
      asm volatile("s_waitcnt vmcnt(12)" ::: "memory");
    } else {
      asm volatile("s_waitcnt vmcnt(0)" ::: "memory");
    }
    __builtin_amdgcn_s_barrier();
    __builtin_amdgcn_sched_barrier(0);
    COMPUTE(1);
    if (kt2 + 2 < NK) {
      WRITEA(0);
      asm volatile("s_waitcnt lgkmcnt(0)" ::: "memory");
    }
  }

#pragma unroll
  for (int n = 0; n < 4; ++n) {
    int col = col0 + wc * 64 + n * 16 + cl;
    float bv = bias[col];
#pragma unroll
    for (int m = 0; m < 8; ++m) {
      int rowb = row0 + wr * 128 + m * 16 + kg * 4;
#pragma unroll
      for (int i = 0; i < 4; ++i) {
        out[(size_t)(rowb + i) * N_DIM + col] = acc[m][n][i] + bv;
      }
    }
  }
#undef LOADA
#undef WRITEA
#undef STAGEB
#undef COMPUTE
}

extern "C" void kernel_launch(void* const* d_in, const int* in_sizes, int n_in,
                              void* d_out, int out_size, void* d_ws, size_t ws_size,
                              hipStream_t stream) {
  const float* x = (const float*)d_in[0];
  const float* w = (const float*)d_in[1];
  const float* bias = (const float*)d_in[2];
  const float* kk = (const float*)d_in[3];
  const float* aa = (const float*)d_in[4];
  float* out = (float*)d_out;

  uint32_t* wb = (uint32_t*)d_ws;  // 2 MB bf16 w_bin at offset 0
  wconv<<<(N_DIM * K_DIM) / (256 * 16), 256, 0, stream>>>(w, kk, aa, wb);

  const int M = in_sizes[0] / K_DIM;  // 32768
  const int grid = (M / BM) * (N_DIM / BN);  // 512

  const size_t wb_bytes = (size_t)N_DIM * K_DIM * 2;  // 2 MB
  const size_t xb_bytes = (size_t)M * K_DIM * 2;      // 64 MB
  if (ws_size >= wb_bytes + xb_bytes) {
    uint32_t* xbp = (uint32_t*)((char*)d_ws + wb_bytes);
    xconv<<<(int)(((size_t)M * K_DIM) / (256 * 16)), 256, 0, stream>>>(x, xbp);
    binlin_gemm4r<<<grid, 512, 0, stream>>>(xbp, wb, bias, out);
  } else {
    binlin_gemm_fb<<<grid, 512, 0, stream>>>(x, wb, bias, out);
  }
}

// Round 10
// 123.504 us; speedup vs baseline: 1.0272x; 1.0272x over previous
//
#include <hip/hip_runtime.h>
#include <stdint.h>

#define K_DIM 1024
#define N_DIM 1024
#define BM 256
#define BN 256
#define BK4 32
#define NT (K_DIM / BK4)           // 32 K-tiles
#define UNIT4_U32 ((BM + BN) * 16) // 32 KB per ring unit (A 16KB + B 16KB)

#define AS1 __attribute__((address_space(1)))
#define AS3 __attribute__((address_space(3)))

typedef __attribute__((ext_vector_type(4))) float f32x4;
typedef __attribute__((ext_vector_type(8))) short bf16x8;
typedef __attribute__((ext_vector_type(4))) uint32_t u32x4;

// round-half-up to bf16, pack two: low 16 = a, high 16 = b
__device__ __forceinline__ uint32_t pack_bf16(float a, float b) {
  uint32_t ua = __builtin_bit_cast(uint32_t, a) + 0x8000u;
  uint32_t ub = __builtin_bit_cast(uint32_t, b) + 0x8000u;
  return __builtin_amdgcn_perm(ub, ua, 0x07060302u);
}

__device__ __forceinline__ float wbin1(float v, float kkv, float aav) {
  float t = v * kkv;
  t = fminf(fmaxf(t, -1.0f), 1.0f);
  return t * aav;
}

// ---------------- kernel 1: w_bin = bf16(aa*clamp(kk*w,-1,1)) into ws ------
__global__ __launch_bounds__(256) void wconv(const float* __restrict__ w,
                                             const float* __restrict__ kkp,
                                             const float* __restrict__ aap,
                                             uint32_t* __restrict__ wb) {
  const float kkv = kkp[0];
  const float aav = aap[0];
  const int g = blockIdx.x * 256 + threadIdx.x;  // 16 floats per thread
  const f32x4* src = (const f32x4*)(w + (size_t)g * 16);
  f32x4 v0 = src[0], v1 = src[1], v2 = src[2], v3 = src[3];
  uint32_t p[8];
#pragma unroll
  for (int i = 0; i < 4; ++i) {
    f32x4 v = i == 0 ? v0 : (i == 1 ? v1 : (i == 2 ? v2 : v3));
    p[2 * i] = pack_bf16(wbin1(v[0], kkv, aav), wbin1(v[1], kkv, aav));
    p[2 * i + 1] = pack_bf16(wbin1(v[2], kkv, aav), wbin1(v[3], kkv, aav));
  }
  u32x4* dst = (u32x4*)(wb + (size_t)g * 8);
  dst[0] = u32x4{p[0], p[1], p[2], p[3]};
  dst[1] = u32x4{p[4], p[5], p[6], p[7]};
}

// ---------------- kernel 2: x fp32 -> bf16 (packed) into ws ----------------
__global__ __launch_bounds__(256) void xconv(const float* __restrict__ x,
                                             uint32_t* __restrict__ xb) {
  const size_t g = (size_t)blockIdx.x * 256 + threadIdx.x;  // 16 floats
  const f32x4* src = (const f32x4*)(x + g * 16);
  f32x4 v0 = src[0], v1 = src[1], v2 = src[2], v3 = src[3];
  uint32_t p[8];
  p[0] = pack_bf16(v0[0], v0[1]); p[1] = pack_bf16(v0[2], v0[3]);
  p[2] = pack_bf16(v1[0], v1[1]); p[3] = pack_bf16(v1[2], v1[3]);
  p[4] = pack_bf16(v2[0], v2[1]); p[5] = pack_bf16(v2[2], v2[3]);
  p[6] = pack_bf16(v3[0], v3[1]); p[7] = pack_bf16(v3[2], v3[3]);
  u32x4* dst = (u32x4*)(xb + g * 8);
  dst[0] = u32x4{p[0], p[1], p[2], p[3]};
  dst[1] = u32x4{p[4], p[5], p[6], p[7]};
}

// ---------------- kernel 3 (fast): 4-ring FREE-RUN GEMM --------------------
// Identical geometry/ring to R9 (256x256 tile, 8 waves 2x4, wave 128x64,
// BK=32, 4-unit 128 KB ring, stage t+3 during t, counted vmcnt 8/4/0), but
// ONE barrier per K-tile (boundary only). Within a tile each wave free-runs
// {12 ds_read_b128 + 2x16 MFMA}: no intra-tile barriers, so one wave's
// ds_reads overlap another's MFMA cluster (LDS port and matrix pipe run
// concurrently instead of alternating). Correctness: unit (t+3)&3 written
// during t was last read in tile t-1, and every wave passed the t-1 boundary
// barrier before any DMA of tile t issues; per-wave vmcnt(8) at boundary +
// barrier-arrival => all waves' staging for t+1 landed before tile t+1 reads.
__global__ __launch_bounds__(512, 2) void binlin_gemm4f(
    const uint32_t* __restrict__ xb, const uint32_t* __restrict__ wb,
    const float* __restrict__ bias, float* __restrict__ out) {
  __shared__ uint32_t lds[4 * UNIT4_U32];  // 128 KB

  const int tid = threadIdx.x;

  // bijective XCD swizzle (grid=512): 4 n-blocks of an m-panel -> same L2
  const int per = gridDim.x >> 3;
  const int logical = (blockIdx.x & 7) * per + (blockIdx.x >> 3);
  const int mIdx = logical >> 2;  // N_DIM/BN = 4
  const int nIdx = logical & 3;
  const int row0 = mIdx * BM;
  const int col0 = nIdx * BN;

  const int w8 = tid >> 6;
  const int lane = tid & 63;
  // staging source mapping (16 rows / op): lane -> row lane>>2, logical
  // slot s = (lane&3) ^ ((lane>>3)&3)  [inverse of phys = kg ^ ((row>>1)&3)]
  const int rl = lane >> 2;
  const int sl = (lane & 3) ^ ((lane >> 3) & 3);
  const uint32_t* ga_base =
      xb + (size_t)(row0 + w8 * 32 + rl) * (K_DIM / 2) + sl * 4;
  const uint32_t* gb_base =
      wb + (size_t)(col0 + w8 * 32 + rl) * (K_DIM / 2) + sl * 4;

  const int wr = w8 >> 2;  // 0..1 (m half)
  const int wc = w8 & 3;   // 0..3 (n quarter)
  const int cl = lane & 15;
  const int kg = lane >> 4;  // 16B k-slot (0..3)

  f32x4 acc[8][4] = {};
  bf16x8 af[8], bfr[2][2];

#define STAGE_A1(kt, SD, c)                                               \
  __builtin_amdgcn_global_load_lds(                                       \
      (const AS1 uint32_t*)(ga_base + (size_t)((c)*16) * (K_DIM / 2) +    \
                            (kt)*16),                                     \
      (AS3 uint32_t*)((SD) + (w8 * 32 + (c)*16) * 16), 16, 0, 0)

#define STAGE_B1(kt, SD, c)                                               \
  __builtin_amdgcn_global_load_lds(                                       \
      (const AS1 uint32_t*)(gb_base + (size_t)((c)*16) * (K_DIM / 2) +    \
                            (kt)*16),                                     \
      (AS3 uint32_t*)((SD) + BM * 16 + (w8 * 32 + (c)*16) * 16), 16, 0, 0)

#define READ_AF(AB)                                                            \
  _Pragma("unroll") for (int m = 0; m < 8; ++m) {                              \
    int rr = wr * 128 + m * 16 + cl;                                           \
    af[m] =                                                                    \
        *(const bf16x8*)((AB) + rr * 16 + ((kg ^ ((rr >> 1) & 3)) * 4));       \
  }

#define READ_BF(BB, NH)                                                        \
  _Pragma("unroll") for (int n = 0; n < 2; ++n) {                              \
    int rr = wc * 64 + ((NH)*2 + n) * 16 + cl;                                 \
    bfr[NH][n] =                                                               \
        *(const bf16x8*)((BB) + rr * 16 + ((kg ^ ((rr >> 1) & 3)) * 4));       \
  }

#define MFMA_CL(NH)                                                            \
  __builtin_amdgcn_s_setprio(1);                                               \
  _Pragma("unroll") for (int m = 0; m < 8; ++m)                                \
  _Pragma("unroll") for (int n = 0; n < 2; ++n)                                \
  acc[m][(NH)*2 + n] = __builtin_amdgcn_mfma_f32_16x16x32_bf16(                \
      af[m], bfr[NH][n], acc[m][(NH)*2 + n], 0, 0, 0);                         \
  __builtin_amdgcn_s_setprio(0);

  // prologue: stage units 0,1,2 (12 DMAs, unit order), retire unit 0 only
#pragma unroll
  for (int u = 0; u < 3; ++u) {
    uint32_t* SD = &lds[u * UNIT4_U32];
    STAGE_A1(u, SD, 0);
    STAGE_A1(u, SD, 1);
    STAGE_B1(u, SD, 0);
    STAGE_B1(u, SD, 1);
  }
  asm volatile("s_waitcnt vmcnt(8)" ::: "memory");
  __builtin_amdgcn_s_barrier();

#pragma unroll 4
  for (int t = 0; t < NT; ++t) {
    const uint32_t* AB = &lds[(t & 3) * UNIT4_U32];
    const uint32_t* BB = AB + BM * 16;
    uint32_t* SD = &lds[((t + 3) & 3) * UNIT4_U32];
    // issue next staging first (latency cover = rest of the tile)
    if (t + 3 < NT) {
      STAGE_A1(t + 3, SD, 0);
      STAGE_A1(t + 3, SD, 1);
      STAGE_B1(t + 3, SD, 0);
      STAGE_B1(t + 3, SD, 1);
    }
    // free-run: 12 ds_read_b128 + 2 clusters of 16 MFMA, no barriers.
    // compiler inserts fine-grained lgkmcnt between reads and MFMAs.
    READ_AF(AB);
    READ_BF(BB, 0);
    READ_BF(BB, 1);
    MFMA_CL(0);
    MFMA_CL(1);
    // tile boundary: counted retire + single barrier
    if (t < NT - 3) {
      asm volatile("s_waitcnt vmcnt(8)" ::: "memory");
    } else if (t == NT - 3) {
      asm volatile("s_waitcnt vmcnt(4)" ::: "memory");
    } else if (t == NT - 2) {
      asm volatile("s_waitcnt vmcnt(0)" ::: "memory");
    }
    __builtin_amdgcn_s_barrier();
  }

  // epilogue: bias + fp32 store
#pragma unroll
  for (int n = 0; n < 4; ++n) {
    int col = col0 + wc * 64 + n * 16 + cl;
    float bv = bias[col];
#pragma unroll
    for (int m = 0; m < 8; ++m) {
      int rowb = row0 + wr * 128 + m * 16 + kg * 4;
#pragma unroll
      for (int i = 0; i < 4; ++i) {
        out[(size_t)(rowb + i) * N_DIM + col] = acc[m][n][i] + bv;
      }
    }
  }
#undef STAGE_A1
#undef STAGE_B1
#undef READ_AF
#undef READ_BF
#undef MFMA_CL
}

// ---------------- fallback GEMM (fused conversion, used when ws small) -----
#define BK 64
#define NK (K_DIM / BK)
__global__ __launch_bounds__(512, 2) void binlin_gemm_fb(
    const float* __restrict__ x, const uint32_t* __restrict__ wb,
    const float* __restrict__ bias, float* __restrict__ out) {
  __shared__ uint32_t lds[2][(BM + BN) * 32];

  const int tid = threadIdx.x;
  const int per = gridDim.x >> 3;
  const int logical = (blockIdx.x & 7) * per + (blockIdx.x >> 3);
  const int mIdx = logical >> 2;
  const int nIdx = logical & 3;
  const int row0 = mIdx * BM;
  const int col0 = nIdx * BN;

  const int r = tid >> 1;
  const int h = tid & 1;
  const int sw = r & 7;
  const float* ga = x + (size_t)(row0 + r) * K_DIM + h * 32;
  const int aoff = r * 32;

  const int w8 = tid >> 6;
  const int lane = tid & 63;
  const int brow = lane >> 3;
  const int bslot = (lane & 7) ^ brow;
  const uint32_t* gb_base =
      wb + (size_t)(col0 + w8 * 32 + brow) * (K_DIM / 2) + bslot * 4;
  const int boff = (w8 * 32) * 32;

  const int wr = w8 >> 2;
  const int wc = w8 & 3;
  const int cl = lane & 15;
  const int kg = lane >> 4;

  f32x4 acc[8][4] = {};
  f32x4 ra[8];

#define LOADA(kt)                                                \
  {                                                              \
    const f32x4* pa = (const f32x4*)(ga + (kt)*BK);              \
    _Pragma("unroll") for (int i = 0; i < 8; ++i) ra[i] = pa[i]; \
  }
#define WRITEA(buf)                                                       \
  {                                                                       \
    uint32_t* lap = &lds[buf][0] + aoff;                                  \
    _Pragma("unroll") for (int j = 0; j < 4; ++j) {                       \
      u32x4 pk = {pack_bf16(ra[2 * j][0], ra[2 * j][1]),                  \
                  pack_bf16(ra[2 * j][2], ra[2 * j][3]),                  \
                  pack_bf16(ra[2 * j + 1][0], ra[2 * j + 1][1]),          \
                  pack_bf16(ra[2 * j + 1][2], ra[2 * j + 1][3])};         \
      *(u32x4*)(lap + (((h * 4 + j) ^ sw) * 4)) = pk;                     \
    }                                                                     \
  }
#define STAGEB(kt, buf)                                                    \
  {                                                                        \
    uint32_t* lbp = &lds[buf][BM * 32] + boff;                             \
    _Pragma("unroll") for (int c = 0; c < 4; ++c) {                        \
      __builtin_amdgcn_global_load_lds(                                    \
          (const AS1 uint32_t*)(gb_base + (size_t)(c * 8) * (K_DIM / 2) +  \
                                (kt)*32),                                  \
          (AS3 uint32_t*)(lbp + c * 8 * 32), 16, 0, 0);                    \
    }                                                                      \
  }
#define COMPUTE(buf)                                                           \
  {                                                                            \
    const uint32_t* A = &lds[buf][0];                                          \
    const uint32_t* B = &lds[buf][BM * 32];                                    \
    _Pragma("unroll") for (int ks = 0; ks < 2; ++ks) {                         \
      bf16x8 bfr[4];                                                           \
      _Pragma("unroll") for (int n = 0; n < 4; ++n) {                          \
        int rr = wc * 64 + n * 16 + cl;                                        \
        bfr[n] =                                                               \
            *(const bf16x8*)(B + rr * 32 + (((ks * 4 + kg) ^ (rr & 7)) * 4));  \
      }                                                                        \
      _Pragma("unroll") for (int mh = 0; mh < 2; ++mh) {                       \
        bf16x8 af[4];                                                          \
        _Pragma("unroll") for (int m = 0; m < 4; ++m) {                        \
          int rr = wr * 128 + (mh * 4 + m) * 16 + cl;                          \
          af[m] =                                                              \
              *(const bf16x8*)(A + rr * 32 + (((ks * 4 + kg) ^ (rr & 7)) * 4));\
        }                                                                      \
        __builtin_amdgcn_s_setprio(1);                                         \
        _Pragma("unroll") for (int m = 0; m < 4; ++m)                          \
            _Pragma("unroll") for (int n = 0; n < 4; ++n)                      \
                acc[mh * 4 + m][n] = __builtin_amdgcn_mfma_f32_16x16x32_bf16(  \
                    af[m], bfr[n], acc[mh * 4 + m][n], 0, 0, 0);               \
        __builtin_amdgcn_s_setprio(0);                                         \
      }                                                                        \
    }                                                                          \
  }

  LOADA(0);
  STAGEB(0, 0);
  WRITEA(0);
  asm volatile("s_waitcnt vmcnt(0) lgkmcnt(0)" ::: "memory");
  __builtin_amdgcn_s_barrier();

  for (int kt2 = 0; kt2 < NK; kt2 += 2) {
    LOADA(kt2 + 1);
    STAGEB(kt2 + 1, 1);
    asm volatile("s_waitcnt vmcnt(12)" ::: "memory");
    __builtin_amdgcn_s_barrier();
    __builtin_amdgcn_sched_barrier(0);
    COMPUTE(0);
    WRITEA(1);
    asm volatile("s_waitcnt lgkmcnt(0)" ::: "memory");
    if (kt2 + 2 < NK) {
      LOADA(kt2 + 2);
      STAGEB(kt2 + 2, 0);
      asm volatile("s_waitcnt vmcnt(12)" ::: "memory");
    } else {
      asm volatile("s_waitcnt vmcnt(0)" ::: "memory");
    }
    __builtin_amdgcn_s_barrier();
    __builtin_amdgcn_sched_barrier(0);
    COMPUTE(1);
    if (kt2 + 2 < NK) {
      WRITEA(0);
      asm volatile("s_waitcnt lgkmcnt(0)" ::: "memory");
    }
  }

#pragma unroll
  for (int n = 0; n < 4; ++n) {
    int col = col0 + wc * 64 + n * 16 + cl;
    float bv = bias[col];
#pragma unroll
    for (int m = 0; m < 8; ++m) {
      int rowb = row0 + wr * 128 + m * 16 + kg * 4;
#pragma unroll
      for (int i = 0; i < 4; ++i) {
        out[(size_t)(rowb + i) * N_DIM + col] = acc[m][n][i] + bv;
      }
    }
  }
#undef LOADA
#undef WRITEA
#undef STAGEB
#undef COMPUTE
}

extern "C" void kernel_launch(void* const* d_in, const int* in_sizes, int n_in,
                              void* d_out, int out_size, void* d_ws, size_t ws_size,
                              hipStream_t stream) {
  const float* x = (const float*)d_in[0];
  const float* w = (const float*)d_in[1];
  const float* bias = (const float*)d_in[2];
  const float* kk = (const float*)d_in[3];
  const float* aa = (const float*)d_in[4];
  float* out = (float*)d_out;

  uint32_t* wb = (uint32_t*)d_ws;  // 2 MB bf16 w_bin at offset 0
  wconv<<<(N_DIM * K_DIM) / (256 * 16), 256, 0, stream>>>(w, kk, aa, wb);

  const int M = in_sizes[0] / K_DIM;  // 32768
  const int grid = (M / BM) * (N_DIM / BN);  // 512

  const size_t wb_bytes = (size_t)N_DIM * K_DIM * 2;  // 2 MB
  const size_t xb_bytes = (size_t)M * K_DIM * 2;      // 64 MB
  if (ws_size >= wb_bytes + xb_bytes) {
    uint32_t* xbp = (uint32_t*)((char*)d_ws + wb_bytes);
    xconv<<<(int)(((size_t)M * K_DIM) / (256 * 16)), 256, 0, stream>>>(x, xbp);
    binlin_gemm4f<<<grid, 512, 0, stream>>>(xbp, wb, bias, out);
  } else {
    binlin_gemm_fb<<<grid, 512, 0, stream>>>(x, wb, bias, out);
  }
}

// Round 11
// 112.933 us; speedup vs baseline: 1.1234x; 1.0936x over previous
//
#include <hip/hip_runtime.h>
#include <stdint.h>

#define K_DIM 1024
#define N_DIM 1024
#define BM 128
#define BN 256
#define BK 32
#define NT (K_DIM / BK)             // 32 K-tiles
#define AOFF_U32 (BM * 16)          // A region: 128 rows x 16 u32 = 2048
#define UNIT_U32 ((BM + BN) * 16)   // 24 KB per ring unit
#define NRING 3                     // 72 KB total -> 2 blocks/CU

#define AS1 __attribute__((address_space(1)))
#define AS3 __attribute__((address_space(3)))

typedef __attribute__((ext_vector_type(4))) float f32x4;
typedef __attribute__((ext_vector_type(8))) short bf16x8;
typedef __attribute__((ext_vector_type(4))) uint32_t u32x4;

// round-half-up to bf16, pack two: low 16 = a, high 16 = b
__device__ __forceinline__ uint32_t pack_bf16(float a, float b) {
  uint32_t ua = __builtin_bit_cast(uint32_t, a) + 0x8000u;
  uint32_t ub = __builtin_bit_cast(uint32_t, b) + 0x8000u;
  return __builtin_amdgcn_perm(ub, ua, 0x07060302u);
}

__device__ __forceinline__ float wbin1(float v, float kkv, float aav) {
  float t = v * kkv;
  t = fminf(fmaxf(t, -1.0f), 1.0f);
  return t * aav;
}

// ---------------- kernel 1: w_bin = bf16(aa*clamp(kk*w,-1,1)) into ws ------
__global__ __launch_bounds__(256) void wconv(const float* __restrict__ w,
                                             const float* __restrict__ kkp,
                                             const float* __restrict__ aap,
                                             uint32_t* __restrict__ wb) {
  const float kkv = kkp[0];
  const float aav = aap[0];
  const int g = blockIdx.x * 256 + threadIdx.x;  // 16 floats per thread
  const f32x4* src = (const f32x4*)(w + (size_t)g * 16);
  f32x4 v0 = src[0], v1 = src[1], v2 = src[2], v3 = src[3];
  uint32_t p[8];
#pragma unroll
  for (int i = 0; i < 4; ++i) {
    f32x4 v = i == 0 ? v0 : (i == 1 ? v1 : (i == 2 ? v2 : v3));
    p[2 * i] = pack_bf16(wbin1(v[0], kkv, aav), wbin1(v[1], kkv, aav));
    p[2 * i + 1] = pack_bf16(wbin1(v[2], kkv, aav), wbin1(v[3], kkv, aav));
  }
  u32x4* dst = (u32x4*)(wb + (size_t)g * 8);
  dst[0] = u32x4{p[0], p[1], p[2], p[3]};
  dst[1] = u32x4{p[4], p[5], p[6], p[7]};
}

// ---------------- kernel 2: fused-convert free-run ring GEMM ---------------
// Tile 128x256, 512 thr = 8 waves (2 wave-rows x 4 wave-cols), wave 64x64
// out (acc 64 VGPR), BK=32, 32 K-tiles. LDS ring of 3 units (A[128][32] +
// B[256][32] bf16 = 24 KB) = 72 KB -> 2 blocks/CU (needs VGPR<=128, forced
// via __launch_bounds__(512,4)). A is reg-staged with FUSED fp32->bf16
// convert (2 f32x4 loads + 8 packs + 1 ds_write_b128 per wave per tile) —
// eliminates the separate 30 us xconv pass. B staged via global_load_lds
// with pre-swizzled source. Free-run body (R10 winner): no intra-tile
// barriers; 1 boundary barrier/tile; counted vmcnt(2) retires B(t+1)+
// A(t+2) only — never 0 until the tail.
// Swizzle (both sides): phys_slot = slot ^ ((row>>1)&3), row stride 16 u32.
__global__ __launch_bounds__(512, 4) void binlin_fused(
    const float* __restrict__ x, const uint32_t* __restrict__ wb,
    const float* __restrict__ bias, float* __restrict__ out) {
  __shared__ uint32_t lds[NRING * UNIT_U32];  // 72 KB

  const int tid = threadIdx.x;

  // bijective XCD swizzle (grid=1024): 4 n-blocks of an m-panel -> same L2
  const int per = gridDim.x >> 3;
  const int logical = (blockIdx.x & 7) * per + (blockIdx.x >> 3);
  const int mIdx = logical >> 2;  // N_DIM/BN = 4
  const int nIdx = logical & 3;
  const int row0 = mIdx * BM;
  const int col0 = nIdx * BN;

  const int w8 = tid >> 6;
  const int lane = tid & 63;

  // ---- A reg-staging: wave w8 covers rows [w8*16, w8*16+16) ----
  const int arow = w8 * 16 + (lane >> 2);       // local row 0..127
  const int aslot = lane & 3;                   // logical 16B k-slot
  const float* ga = x + (size_t)(row0 + arow) * K_DIM + aslot * 8;
  const int awidx = arow * 16 + ((aslot ^ ((arow >> 1) & 3)) * 4);

  // ---- B staging via global_load_lds: wave w8 rows [w8*32, +32), 2 ops ----
  const int rl = lane >> 2;
  const int sl = (lane & 3) ^ ((lane >> 3) & 3);  // pre-swizzled source slot
  const uint32_t* gb_base =
      wb + (size_t)(col0 + w8 * 32 + rl) * (K_DIM / 2) + sl * 4;

  // ---- compute indices ----
  const int wr = w8 >> 2;   // 0..1
  const int wc = w8 & 3;    // 0..3
  const int cl = lane & 15;
  const int kg = lane >> 4;

  f32x4 acc[4][4] = {};
  bf16x8 af[4], bfr[2];
  f32x4 aA, aB;  // in-flight A fp32 (issued at tile start, packed at end)

#define STAGE_B1(kt, SD, c)                                               \
  __builtin_amdgcn_global_load_lds(                                       \
      (const AS1 uint32_t*)(gb_base + (size_t)((c)*16) * (K_DIM / 2) +    \
                            (kt)*16),                                     \
      (AS3 uint32_t*)((SD) + AOFF_U32 + (w8 * 32 + (c)*16) * 16), 16, 0, 0)

#define LOAD_A(kt)                                        \
  do {                                                    \
    aA = *(const f32x4*)(ga + (kt)*32);                   \
    aB = *(const f32x4*)(ga + (kt)*32 + 4);               \
  } while (0)

#define PACK_WRITE_A(SD)                                                  \
  do {                                                                    \
    u32x4 pk = {pack_bf16(aA[0], aA[1]), pack_bf16(aA[2], aA[3]),         \
                pack_bf16(aB[0], aB[1]), pack_bf16(aB[2], aB[3])};        \
    *(u32x4*)((SD) + awidx) = pk;                                         \
  } while (0)

#define READ_AF(AB)                                                            \
  _Pragma("unroll") for (int m = 0; m < 4; ++m) {                              \
    int rr = wr * 64 + m * 16 + cl;                                            \
    af[m] =                                                                    \
        *(const bf16x8*)((AB) + rr * 16 + ((kg ^ ((rr >> 1) & 3)) * 4));       \
  }

#define READ_BF(BB, NH)                                                        \
  _Pragma("unroll") for (int n = 0; n < 2; ++n) {                              \
    int rr = wc * 64 + ((NH)*2 + n) * 16 + cl;                                 \
    bfr[n] =                                                                   \
        *(const bf16x8*)((BB) + rr * 16 + ((kg ^ ((rr >> 1) & 3)) * 4));       \
  }

#define MFMA_CL(NH)                                                            \
  __builtin_amdgcn_s_setprio(1);                                               \
  _Pragma("unroll") for (int m = 0; m < 4; ++m)                                \
  _Pragma("unroll") for (int n = 0; n < 2; ++n)                                \
  acc[m][(NH)*2 + n] = __builtin_amdgcn_mfma_f32_16x16x32_bf16(                \
      af[m], bfr[n], acc[m][(NH)*2 + n], 0, 0, 0);                             \
  __builtin_amdgcn_s_setprio(0);

  // ---- prologue: stage units 0 and 1 ----
  // issue order: A(0) 2, A(1) 2, B(0) 2, B(1) 2
  f32x4 p0a = *(const f32x4*)(ga + 0);
  f32x4 p0b = *(const f32x4*)(ga + 4);
  f32x4 p1a = *(const f32x4*)(ga + 32);
  f32x4 p1b = *(const f32x4*)(ga + 36);
  STAGE_B1(0, &lds[0], 0);
  STAGE_B1(0, &lds[0], 1);
  STAGE_B1(1, &lds[UNIT_U32], 0);
  STAGE_B1(1, &lds[UNIT_U32], 1);
  {
    u32x4 pk0 = {pack_bf16(p0a[0], p0a[1]), pack_bf16(p0a[2], p0a[3]),
                 pack_bf16(p0b[0], p0b[1]), pack_bf16(p0b[2], p0b[3])};
    *(u32x4*)(&lds[0] + awidx) = pk0;  // auto-waits the A(0) loads
    u32x4 pk1 = {pack_bf16(p1a[0], p1a[1]), pack_bf16(p1a[2], p1a[3]),
                 pack_bf16(p1b[0], p1b[1]), pack_bf16(p1b[2], p1b[3])};
    *(u32x4*)(&lds[UNIT_U32] + awidx) = pk1;
  }
  asm volatile("s_waitcnt vmcnt(2)" ::: "memory");  // retire B(0), keep B(1)
  asm volatile("s_waitcnt lgkmcnt(0)" ::: "memory");
  __builtin_amdgcn_s_barrier();

  // ---- main loop: invariant at entry of tile t: outstanding = 2 B(t+1) ----
  int cu = 0, su = 2;
  for (int t = 0; t < NT; ++t) {
    const uint32_t* AB = &lds[cu * UNIT_U32];
    const uint32_t* BB = AB + AOFF_U32;
    uint32_t* SD = &lds[su * UNIT_U32];
    const bool more = (t + 2) < NT;
    if (more) {
      LOAD_A(t + 2);        // 2 vmem (regs, packed at end of this tile)
      STAGE_B1(t + 2, SD, 0);  // 2 vmem (DMA to unit (t+2)%3, free since
      STAGE_B1(t + 2, SD, 1);  //   all waves passed the t-1 barrier)
    }
    // free-run: ds_reads + 2x8 MFMA, no barriers; compiler inserts lgkm.
    READ_AF(AB);
    READ_BF(BB, 0);
    MFMA_CL(0);
    READ_BF(BB, 1);
    MFMA_CL(1);
    // end-of-tile: counted retire + pack A + single barrier
    if (more) {
      asm volatile("s_waitcnt vmcnt(2)" ::: "memory");  // B(t+1)+A(t+2) done
      PACK_WRITE_A(SD);
      asm volatile("s_waitcnt lgkmcnt(0)" ::: "memory");
      __builtin_amdgcn_s_barrier();
    } else if (t == NT - 2) {
      asm volatile("s_waitcnt vmcnt(0)" ::: "memory");  // drain B(NT-1)
      __builtin_amdgcn_s_barrier();
    }
    cu = (cu == NRING - 1) ? 0 : cu + 1;
    su = (su == NRING - 1) ? 0 : su + 1;
  }

  // ---- epilogue: bias + fp32 store ----
#pragma unroll
  for (int n = 0; n < 4; ++n) {
    int col = col0 + wc * 64 + n * 16 + cl;
    float bv = bias[col];
#pragma unroll
    for (int m = 0; m < 4; ++m) {
      int rowb = row0 + wr * 64 + m * 16 + kg * 4;
#pragma unroll
      for (int i = 0; i < 4; ++i) {
        out[(size_t)(rowb + i) * N_DIM + col] = acc[m][n][i] + bv;
      }
    }
  }
#undef STAGE_B1
#undef LOAD_A
#undef PACK_WRITE_A
#undef READ_AF
#undef READ_BF
#undef MFMA_CL
}

extern "C" void kernel_launch(void* const* d_in, const int* in_sizes, int n_in,
                              void* d_out, int out_size, void* d_ws, size_t ws_size,
                              hipStream_t stream) {
  const float* x = (const float*)d_in[0];
  const float* w = (const float*)d_in[1];
  const float* bias = (const float*)d_in[2];
  const float* kk = (const float*)d_in[3];
  const float* aa = (const float*)d_in[4];
  float* out = (float*)d_out;

  uint32_t* wb = (uint32_t*)d_ws;  // 2 MB bf16 w_bin
  wconv<<<(N_DIM * K_DIM) / (256 * 16), 256, 0, stream>>>(w, kk, aa, wb);

  const int M = in_sizes[0] / K_DIM;         // 32768
  const int grid = (M / BM) * (N_DIM / BN);  // 256 * 4 = 1024
  binlin_fused<<<grid, 512, 0, stream>>>(x, wb, bias, out);
}